// Round 15
// baseline (253.960 us; speedup 1.0000x reference)
//
#include <hip/hip_runtime.h>
#include <cmath>

#define TPB   128                 // threads per block (2 waves); each thread owns 4 cols
#define TH    16                  // output rows per block tile (22 input rows)
#define WID   512
#define HEI   512
#define NIMG  64
#define NTILE (HEI / TH)          // 32
#define NBLK  (NIMG * NTILE)      // 2048

// LEDGER: R14 best 50.1us (56 VGPR, VALUBusy 51%, occ 35%) — stall is
// exposed per-stage load latency. All CROSS-stage prefetch variants spill
// (R2,R3,R9,R13). R15: merge TWO rows into ONE stage scope — all 12 loads
// issued at top, row b's latency hidden under row a's compute, row a's
// latency exposed once per 2 rows. No value crosses a stage boundary, so
// lifetimes close in-scope (the only pattern the allocator handles well).
// Peak live ~115-120 regs -> (,2) cap = 128 should hold.

typedef _Float16 h2 __attribute__((ext_vector_type(2)));

struct GW { unsigned int wh[7]; };   // f16 weight broadcast pairs (lo==hi), SGPR-resident

__device__ __forceinline__ h2 pkrtz(float a, float b) {
    return __builtin_bit_cast(h2, __builtin_amdgcn_cvt_pkrtz(a, b));
}
__device__ __forceinline__ h2 fma2(h2 a, h2 b, h2 c) { return __builtin_elementwise_fma(a, b, c); }

// Issue the 6 float4 loads for input row gy (zero-filled if out of range /
// edge-clamped lanes). Pure loads — no consumption here.
__device__ __forceinline__ void load6(int gy, int m, int c0, int clm, int clp,
                                      const float* __restrict__ pb,
                                      const float* __restrict__ tb,
                                      float4& v0, float4& v1, float4& v2,
                                      float4& u0, float4& u1, float4& u2)
{
    if (gy >= 0 && gy < HEI) {
        const float* pr = pb + (size_t)gy * WID;
        const float* tr = tb + (size_t)gy * WID;
        v0 = *(const float4*)(pr + clm);
        v1 = *(const float4*)(pr + c0);
        v2 = *(const float4*)(pr + clp);
        u0 = *(const float4*)(tr + clm);
        u1 = *(const float4*)(tr + c0);
        u2 = *(const float4*)(tr + clp);
        if (m == 0)       { v0 = make_float4(0.f,0.f,0.f,0.f); u0 = make_float4(0.f,0.f,0.f,0.f); }
        if (m == TPB - 1) { v2 = make_float4(0.f,0.f,0.f,0.f); u2 = make_float4(0.f,0.f,0.f,0.f); }
    } else {
        const float4 z = make_float4(0.f, 0.f, 0.f, 0.f);
        v0 = z; v1 = z; v2 = z; u0 = z; u1 = z; u2 = z;
    }
}

// Convert + H-blur one row (from its 6 loaded float4s) into ring slot SL;
// if VB, also V-blur the ring (row SL is newest) + SSIM accumulate.
template <int SL, bool VB>
__device__ __forceinline__ void process_row(
    float4 v0, float4 v1, float4 v2, float4 u0, float4 u1, float4 u2,
    const h2 (&w2)[7],
    h2 (&rAB)[7][4], h2 (&rST)[7][4],
    float& acc)
{
    float pa[12], ta[12];
    pa[0]=v0.x; pa[1]=v0.y; pa[2]=v0.z; pa[3]=v0.w;
    pa[4]=v1.x; pa[5]=v1.y; pa[6]=v1.z; pa[7]=v1.w;
    pa[8]=v2.x; pa[9]=v2.y; pa[10]=v2.z; pa[11]=v2.w;
    ta[0]=u0.x; ta[1]=u0.y; ta[2]=u0.z; ta[3]=u0.w;
    ta[4]=u1.x; ta[5]=u1.y; ta[6]=u1.z; ta[7]=u1.w;
    ta[8]=u2.x; ta[9]=u2.y; ta[10]=u2.z; ta[11]=u2.w;

    // window col k = image column (c0 - 3 + k); output col c uses k = c..c+6
    h2 sd[10], sq[10];
#pragma unroll
    for (int k = 0; k < 10; ++k) {
        const float s = pa[k + 1] + ta[k + 1];
        const float d = pa[k + 1] - ta[k + 1];
        sd[k] = pkrtz(s, d);        // (s, d) packed per column
        sq[k] = sd[k] * sd[k];      // (s^2, d^2)
    }

#pragma unroll
    for (int c = 0; c < 4; ++c) {
        h2 ab = w2[0] * sd[c];
        h2 st = w2[0] * sq[c];
#pragma unroll
        for (int i = 1; i < 7; ++i) {
            ab = fma2(w2[i], sd[c + i], ab);
            st = fma2(w2[i], sq[c + i], st);
        }
        rAB[SL][c] = ab;
        rST[SL][c] = st;
    }

    if constexpr (VB) {
        const float C1 = 1e-4f, C2 = 9e-4f;
#pragma unroll
        for (int c = 0; c < 4; ++c) {
            h2 vAB = w2[0] * rAB[(SL + 1) % 7][c];
            h2 vST = w2[0] * rST[(SL + 1) % 7][c];
#pragma unroll
            for (int j = 1; j < 7; ++j) {
                const int sl = (SL + 1 + j) % 7;   // compile-time
                vAB = fma2(w2[j], rAB[sl][c], vAB);
                vST = fma2(w2[j], rST[sl][c], vST);
            }
            const float fA = (float)vAB[0], fB = (float)vAB[1];
            const float fS = (float)vST[0], fT = (float)vST[1];
            const float A2 = fA * fA, B2 = fB * fB;
            const float muct2 = 0.5f * (A2 - B2);   // 2*mu_p*mu_t
            const float muss  = 0.5f * (A2 + B2);   // mu_p^2 + mu_t^2
            const float ptb2  = 0.5f * (fS - fT);   // 2*blur(p*t)
            const float ssb   = 0.5f * (fS + fT);   // blur(p^2 + t^2)
            const float num = (muct2 + C1) * (ptb2 - muct2 + C2);
            const float den = (muss + C1) * (ssb - muss + C2);
            acc += num * __builtin_amdgcn_rcpf(den);
        }
    }
}

// Merged 2-row stage: rows IYA (slot IYA%7) and IYA+1 (slot (IYA+1)%7).
// All 12 loads issue first; row b's latency hides under row a's compute.
template <int IYA>
__device__ __forceinline__ void ssim_stage2(
    int oy0, int m, int c0, int clm, int clp,
    const float* __restrict__ pb, const float* __restrict__ tb,
    const h2 (&w2)[7],
    h2 (&rAB)[7][4], h2 (&rST)[7][4],
    float& acc)
{
    constexpr int SLa = IYA % 7;
    constexpr int SLb = (IYA + 1) % 7;
    const int gya = oy0 - 3 + IYA;

    float4 a0, a1, a2, a3, a4, a5;
    float4 b0, b1, b2, b3, b4, b5;
    load6(gya,     m, c0, clm, clp, pb, tb, a0, a1, a2, a3, a4, a5);
    load6(gya + 1, m, c0, clm, clp, pb, tb, b0, b1, b2, b3, b4, b5);

    process_row<SLa, (IYA     >= 6)>(a0, a1, a2, a3, a4, a5, w2, rAB, rST, acc);
    process_row<SLb, (IYA + 1 >= 6)>(b0, b1, b2, b3, b4, b5, w2, rAB, rST, acc);
}

__global__ __launch_bounds__(TPB, 2)
void ssim_main_k(const float* __restrict__ pred,
                 const float* __restrict__ targ,
                 float* __restrict__ partial,   // NBLK floats (d_ws), or null
                 float* __restrict__ outacc,    // fallback atomic accumulator
                 GW gw)
{
    const int m    = threadIdx.x;
    const int bid  = blockIdx.x;
    const int img  = bid >> 5;            // NTILE == 32
    const int tile = bid & (NTILE - 1);
    const int oy0  = tile * TH;

    h2 w2[7];
#pragma unroll
    for (int j = 0; j < 7; ++j) w2[j] = __builtin_bit_cast(h2, gw.wh[j]);

    const size_t ioff = (size_t)img * (WID * HEI);
    const float* pb = pred + ioff;
    const float* tb = targ + ioff;

    const int c0  = 4 * m;
    const int clm = (m == 0) ? 0 : (c0 - 4);          // clamped (value zeroed)
    const int clp = (m == TPB - 1) ? c0 : (c0 + 4);   // clamped (value zeroed)

    h2 rAB[7][4], rST[7][4];    // ring: [slot][col], (A,B) and (S,T) packed
    float acc = 0.f;

    // 22 input rows = 11 merged stages; slots are compile-time (IYA % 7)
    ssim_stage2< 0>(oy0, m, c0, clm, clp, pb, tb, w2, rAB, rST, acc);
    ssim_stage2< 2>(oy0, m, c0, clm, clp, pb, tb, w2, rAB, rST, acc);
    ssim_stage2< 4>(oy0, m, c0, clm, clp, pb, tb, w2, rAB, rST, acc);
    ssim_stage2< 6>(oy0, m, c0, clm, clp, pb, tb, w2, rAB, rST, acc);
    ssim_stage2< 8>(oy0, m, c0, clm, clp, pb, tb, w2, rAB, rST, acc);
    ssim_stage2<10>(oy0, m, c0, clm, clp, pb, tb, w2, rAB, rST, acc);
    ssim_stage2<12>(oy0, m, c0, clm, clp, pb, tb, w2, rAB, rST, acc);
    ssim_stage2<14>(oy0, m, c0, clm, clp, pb, tb, w2, rAB, rST, acc);
    ssim_stage2<16>(oy0, m, c0, clm, clp, pb, tb, w2, rAB, rST, acc);
    ssim_stage2<18>(oy0, m, c0, clm, clp, pb, tb, w2, rAB, rST, acc);
    ssim_stage2<20>(oy0, m, c0, clm, clp, pb, tb, w2, rAB, rST, acc);

    // block reduction: wave shfl tree, then cross-wave via LDS
#pragma unroll
    for (int off = 32; off > 0; off >>= 1)
        acc += __shfl_down(acc, off, 64);
    __shared__ float wpart[TPB / 64];
    if ((m & 63) == 0) wpart[m >> 6] = acc;
    __syncthreads();
    if (m == 0) {
        const float tot = wpart[0] + wpart[1];
        if (partial) partial[bid] = tot;
        else atomicAdd(outacc, tot);
    }
}

__global__ void ssim_finalize_k(const float* __restrict__ partial,
                                float* __restrict__ out, int usews)
{
    const float invN = 1.0f / (float)((size_t)NIMG * WID * HEI);
    if (usews) {
        float s = 0.f;
        for (int i = threadIdx.x; i < NBLK; i += 256) s += partial[i];
#pragma unroll
        for (int off = 32; off > 0; off >>= 1) s += __shfl_down(s, off, 64);
        __shared__ float wp[4];
        if ((threadIdx.x & 63) == 0) wp[threadIdx.x >> 6] = s;
        __syncthreads();
        if (threadIdx.x == 0) out[0] = 1.0f - (wp[0] + wp[1] + wp[2] + wp[3]) * invN;
    } else {
        if (threadIdx.x == 0) out[0] = 1.0f - out[0] * invN;
    }
}

// host f32 -> f16 bits, round-to-nearest-even (weights are normal, positive)
static unsigned short f32_to_f16(float f) {
    union { float f; unsigned int u; } c; c.f = f;
    const unsigned int u = c.u;
    const int exp = (int)((u >> 23) & 0xFF) - 127 + 15;
    const unsigned int man = u & 0x7FFFFFu;
    if (exp <= 0) return 0;
    unsigned int base = ((unsigned int)exp << 10) | (man >> 13);
    const unsigned int rem = man & 0x1FFFu;
    base += (rem > 0x1000u) || (rem == 0x1000u && (base & 1u));
    return (unsigned short)base;
}
static float f16_to_f32(unsigned short h) {
    const int exp = (h >> 10) & 0x1F;
    const unsigned int man = h & 0x3FFu;
    if (exp == 0) return 0.f;
    union { unsigned int u; float f; } c;
    c.u = ((unsigned int)(exp - 15 + 127) << 23) | (man << 13);
    return c.f;
}

extern "C" void kernel_launch(void* const* d_in, const int* in_sizes, int n_in,
                              void* d_out, int out_size, void* d_ws, size_t ws_size,
                              hipStream_t stream)
{
    const float* pred = (const float*)d_in[0];
    const float* targ = (const float*)d_in[1];
    float* out = (float*)d_out;

    GW gw;
    {
        double g[7], s = 0.0;
        for (int i = 0; i < 7; ++i) {
            const double c = (double)(i - 3);
            g[i] = exp(-c * c / (2.0 * 1.5 * 1.5));
            s += g[i];
        }
        unsigned short h16[7];
        for (int i = 0; i < 7; ++i) h16[i] = f32_to_f16((float)(g[i] / s));
        // renormalize so the f16 weights sum as close to 1.0 as representable:
        // center tap = round_f16(1 - sum(others)) kills the systematic bias.
        float so = 0.f;
        for (int i = 0; i < 7; ++i) if (i != 3) so += f16_to_f32(h16[i]);
        h16[3] = f32_to_f16(1.0f - so);
        for (int i = 0; i < 7; ++i)
            gw.wh[i] = (unsigned int)h16[i] | ((unsigned int)h16[i] << 16);
    }

    const bool usews = (ws_size >= NBLK * sizeof(float));
    float* partial = usews ? (float*)d_ws : nullptr;
    if (!usews) (void)hipMemsetAsync(d_out, 0, sizeof(float), stream);

    ssim_main_k<<<NBLK, TPB, 0, stream>>>(pred, targ, partial, out, gw);
    ssim_finalize_k<<<1, 256, 0, stream>>>(partial, out, usews ? 1 : 0);
}